// Round 18
// baseline (129.942 us; speedup 1.0000x reference)
//
#include <hip/hip_runtime.h>

// HSTU attention layer: B=2, L=2048, D=1024, H=16, DK=64
// Pipeline: fused fp32->bf16 cvt (+key bitmask; W_q pre-scaled by 0.125*log2e)
// -> QKVU GEMM (256^2 8-phase; V written as swizzled V^T tile images) ->
// flash HSTU attention (swapped 32x32x16, no-max softmax, ones-MFMA row-sum,
// NO setprio fences in the loop, 8 waves, 2-way KV-split) -> gated bf16 ->
// out GEMM (64x128 m97).

#define L_SEQ 2048

typedef __attribute__((ext_vector_type(8))) short bf16x8;     // MFMA A/B frag
typedef __attribute__((ext_vector_type(8))) unsigned short u16x8;
typedef __attribute__((ext_vector_type(4))) float f32x4;      // 16x16 C/D frag
typedef __attribute__((ext_vector_type(16))) float f32x16;    // 32x32 C/D frag

#if __has_builtin(__builtin_amdgcn_exp2f)
#define EXP2F __builtin_amdgcn_exp2f
#else
#define EXP2F __builtin_exp2f
#endif

__device__ __forceinline__ unsigned short f2bf(float f) {
  union { float f; unsigned u; } c; c.f = f;
  unsigned r = c.u + 0x7FFFu + ((c.u >> 16) & 1u);   // RNE
  return (unsigned short)(r >> 16);
}
__device__ __forceinline__ float bf2f(unsigned short h) {
  union { unsigned u; float f; } c; c.u = ((unsigned)h) << 16;
  return c.f;
}

// async global->LDS, 16B/lane. LDS dest = wave-uniform base + lane*16 (linear).
__device__ __forceinline__ void async16(const void* g, void* l) {
  __builtin_amdgcn_global_load_lds((__attribute__((address_space(1))) void*)g,
                                   (__attribute__((address_space(3))) void*)l,
                                   16, 0, 0);
}

__device__ __forceinline__ unsigned cvtpk_bf16(float lo, float hi) {
  unsigned r; asm("v_cvt_pk_bf16_f32 %0, %1, %2" : "=v"(r) : "v"(lo), "v"(hi));
  return r;
}

// ------- fused convert: x | Wq(scaled) | Wk | Wv | Wu | Wo  + key bitmask ----
// blocks 0..9215: converts.  blocks 9216..9231: "always-allowed" mask words.
__global__ __launch_bounds__(256) void cvt_all(
    const float* __restrict__ x,
    const float* __restrict__ wq, const float* __restrict__ wk,
    const float* __restrict__ wv, const float* __restrict__ wu,
    const float* __restrict__ wo,
    unsigned short* __restrict__ xb, unsigned short* __restrict__ wcat,
    const int* __restrict__ tt, const int* __restrict__ sl,
    unsigned* __restrict__ allowed) {
  if (blockIdx.x >= 9216) {                          // mask blocks
    const int k = blockIdx.x - 9216;                 // 0..15
    const int wv64 = (k << 2) + (threadIdx.x >> 6);  // wave unit 0..63
    const int b = wv64 >> 5, w32 = wv64 & 31;
    const int lane = threadIdx.x & 63;
    const int j = w32 * 64 + lane;
    const unsigned long long m = __ballot((tt[b * L_SEQ + j] < 3) && (j < sl[b]));
    if (lane == 0) {
      allowed[b * 64 + 2 * w32]     = (unsigned)m;
      allowed[b * 64 + 2 * w32 + 1] = (unsigned)(m >> 32);
    }
    return;
  }
  const int seg = blockIdx.x >> 10;
  const float* s;
  unsigned short* d;
  float sc = 1.0f;
  if (seg < 4)      { s = x + (size_t)seg * 1048576;  d = xb + (size_t)seg * 1048576; }
  else {
    const int ws = seg - 4;
    s = ws == 0 ? wq : ws == 1 ? wk : ws == 2 ? wv : ws == 3 ? wu : wo;
    d = wcat + (size_t)ws * 1048576;                  // Wo lands right after Wu (=wob)
    if (ws == 0) sc = 0.18033688011112042f;           // 0.125 * log2(e)
  }
  const int i = ((blockIdx.x & 1023) * 256 + threadIdx.x) * 4;
  const float4 v = *reinterpret_cast<const float4*>(s + i);
  ushort4 o;
  o.x = f2bf(v.x * sc); o.y = f2bf(v.y * sc); o.z = f2bf(v.z * sc); o.w = f2bf(v.w * sc);
  *reinterpret_cast<ushort4*>(d + i) = o;
}

// ---------------- GEMM1: 256x256 tile, BK=64, 8 waves, phase-split ----------
// Out: FOUR 4096x1024 matrices Q|K|V|U at Cb + mi*4M elems.  V-region blocks
// write swizzled 64x64 V^T tile images (attn's exact LDS image).
__global__ __launch_bounds__(512, 2) void gemm256_bt(
    const unsigned short* __restrict__ A,
    const unsigned short* __restrict__ BT,
    unsigned short* __restrict__ Cb, int K)
{
  __shared__ char smem[131072];

  const int tid = threadIdx.x, w = tid >> 6, lane = tid & 63;
  const int lo = lane & 15, hi = lane >> 4;
  const int wm = w >> 2, wn = w & 3;
  const int d = blockIdx.x;
  const int lin = (d & 7) * 32 + (d >> 3);           // XCD swizzle (256%8==0)
  const int i0 = (lin >> 4) * 256, j0 = (lin & 15) * 256;

  const int rr = lane >> 3, ch = lane & 7;
  const int ksw = 8 * (ch ^ rr);                     // pre-swizzled k offset

  auto stage = [&](int buf, int t) {
    const size_t k0 = (size_t)t * 64 + ksw;
    #pragma unroll
    for (int q = 0; q < 2; ++q) {
      const int p = 2 * w + q;                       // window 0..15 (8 rows each)
      const int row = 8 * p + rr;
      #pragma unroll
      for (int h = 0; h < 2; ++h) {
        async16(A  + (size_t)(i0 + h * 128 + row) * K + k0,
                smem + buf * 32768 + h * 16384 + p * 1024);
        async16(BT + (size_t)(j0 + h * 128 + row) * K + k0,
                smem + 65536 + buf * 32768 + h * 16384 + p * 1024);
      }
    }
  };

  f32x4 acc[8][4] = {};
  stage(0, 0);

  const int nt = K >> 6;                             // 16 K-tiles
  for (int u = 0; u < nt; ++u) {
    const int buf = u & 1;
    if (u + 1 < nt) {
      stage(buf ^ 1, u + 1);
      asm volatile("s_waitcnt vmcnt(8)" ::: "memory");  // tile u landed; u+1 in flight
    } else {
      asm volatile("s_waitcnt vmcnt(0)" ::: "memory");
    }
    __builtin_amdgcn_s_barrier();
    __builtin_amdgcn_sched_barrier(0);

    const char* Ah = smem + buf * 32768 + wm * 16384;              // this wave's A half
    const char* Bh = smem + 65536 + buf * 32768 + (wn >> 1) * 16384;
    const int brow0 = (wn & 1) * 64;

    bf16x8 bfr[4][2];                                // B frags cached for the tile
    #pragma unroll
    for (int n = 0; n < 4; ++n)
      #pragma unroll
      for (int ks = 0; ks < 2; ++ks)
        bfr[n][ks] = *reinterpret_cast<const bf16x8*>(
            Bh + (brow0 + n * 16 + lo) * 128 + 16 * ((ks * 4 + hi) ^ (lo & 7)));

    #pragma unroll
    for (int ph = 0; ph < 4; ++ph) {
      bf16x8 afr[2][2];
      #pragma unroll
      for (int mm = 0; mm < 2; ++mm)
        #pragma unroll
        for (int ks = 0; ks < 2; ++ks)
          afr[mm][ks] = *reinterpret_cast<const bf16x8*>(
              Ah + ((ph * 2 + mm) * 16 + lo) * 128 + 16 * ((ks * 4 + hi) ^ (lo & 7)));
      __builtin_amdgcn_s_barrier();
      __builtin_amdgcn_sched_barrier(0);
      __builtin_amdgcn_s_setprio(1);
      #pragma unroll
      for (int ks = 0; ks < 2; ++ks)
        #pragma unroll
        for (int mm = 0; mm < 2; ++mm)
          #pragma unroll
          for (int n = 0; n < 4; ++n)
            acc[ph * 2 + mm][n] = __builtin_amdgcn_mfma_f32_16x16x32_bf16(
                afr[mm][ks], bfr[n][ks], acc[ph * 2 + mm][n], 0, 0, 0);
      __builtin_amdgcn_s_setprio(0);
      __builtin_amdgcn_s_barrier();
      __builtin_amdgcn_sched_barrier(0);
    }
  }

  // ---- epilogue ----
  const int mi = (lin & 15) >> 2;                    // 0:Q 1:K 2:V 3:U
  const int cb0 = j0 & 1023;                         // col base within the matrix
  if (mi != 2) {
    unsigned short* base = Cb + (size_t)mi * 4194304;
    #pragma unroll
    for (int m = 0; m < 8; ++m) {
      const int row = i0 + wm * 128 + m * 16 + hi * 4;
      #pragma unroll
      for (int n = 0; n < 4; ++n) {
        const int col = cb0 + wn * 64 + n * 16 + lo;
        #pragma unroll
        for (int r = 0; r < 4; ++r)
          base[(size_t)(row + r) * 1024 + col] = f2bf(acc[m][n][r]);
      }
    }
  } else {
    // all waves are past the final K-loop barrier -> smem is free
    #pragma unroll
    for (int m = 0; m < 8; ++m) {
      const int tl = (wm << 1) + (m >> 2);           // 64-token tile within block
      #pragma unroll
      for (int n = 0; n < 4; ++n) {
        const int dd = n * 16 + lo;
        char* ib = smem + (tl * 4 + wn) * 8192 + dd * 128;
        const int swd = dd & 7;
        #pragma unroll
        for (int r = 0; r < 4; ++r) {
          const int k = (m * 16 + hi * 4 + r) & 63;
          *(unsigned short*)(ib + 16 * ((k >> 3) ^ swd) + 2 * (k & 7)) =
              f2bf(acc[m][n][r]);
        }
      }
    }
    __builtin_amdgcn_s_barrier();
    unsigned short* V = Cb + (size_t)2 * 4194304;
    const int bI = i0 >> 11;
    const int t0 = (i0 & 2047) >> 6;
    const int h0 = cb0 >> 6;
    #pragma unroll
    for (int img = 0; img < 16; ++img) {
      const int tl = img >> 2, hl = img & 3;
      const size_t ob = ((size_t)(bI * 16 + h0 + hl) * 32 + (t0 + tl)) * 4096;
      *reinterpret_cast<u16x8*>(V + ob + tid * 8) =
          *reinterpret_cast<const u16x8*>(smem + img * 8192 + tid * 16);
    }
  }
}

// ---------------- GEMM (m97): C = A * BT^T, MF*32 x 128 tile ----------------
template<int OUT_BF16, int MF>
__global__ __launch_bounds__(256) void gemm_bt(
    const unsigned short* __restrict__ A,
    const unsigned short* __restrict__ BT,
    float* __restrict__ Cf, unsigned short* __restrict__ Cb,
    int M, int N, int K, int cpx, int nbxm, int nbxs)
{
  __shared__ unsigned short As[2][MF * 32 * 32];
  __shared__ unsigned short Bs[2][128 * 32];

  const int tid = threadIdx.x;
  const int w = tid >> 6, lane = tid & 63;
  const int lo = lane & 15, hi = lane >> 4;
  const int d = blockIdx.x + gridDim.x * blockIdx.y;
  const int lin = (d & 7) * cpx + (d >> 3);
  const int i0 = (lin >> nbxs) * (MF * 32), j0 = (lin & nbxm) * 128;
  const int wr = w >> 1, wc = w & 1;
  const int rsub = lane >> 2, csub = (lane & 3) * 8;

  f32x4 acc[MF][4] = {};

  auto stage = [&](int buf, int k0) {
    #pragma unroll
    for (int q = 0; q < 2; ++q) {
      const int cB = w * 2 + q;
      async16(BT + (size_t)(j0 + cB * 16 + rsub) * K + k0 + csub, &Bs[buf][cB * 512]);
      if (q < MF / 2) {
        const int cA = w * (MF / 2) + q;
        async16(A + (size_t)(i0 + cA * 16 + rsub) * K + k0 + csub, &As[buf][cA * 512]);
      }
    }
  };

  stage(0, 0);
  __syncthreads();

  const int nt = K >> 5;
  for (int t = 0; t < nt; ++t) {
    const int buf = t & 1;
    if (t + 1 < nt) stage(buf ^ 1, (t + 1) << 5);
    bf16x8 a[MF], b[4];
    #pragma unroll
    for (int m = 0; m < MF; ++m)
      a[m] = *reinterpret_cast<const bf16x8*>(
          &As[buf][(wr * (MF * 16) + m * 16 + lo) * 32 + hi * 8]);
    #pragma unroll
    for (int n = 0; n < 4; ++n)
      b[n] = *reinterpret_cast<const bf16x8*>(&Bs[buf][(wc * 64 + n * 16 + lo) * 32 + hi * 8]);
    #pragma unroll
    for (int m = 0; m < MF; ++m)
      #pragma unroll
      for (int n = 0; n < 4; ++n)
        acc[m][n] = __builtin_amdgcn_mfma_f32_16x16x32_bf16(a[m], b[n], acc[m][n], 0, 0, 0);
    __syncthreads();
  }

  #pragma unroll
  for (int m = 0; m < MF; ++m) {
    const int row = i0 + wr * (MF * 16) + m * 16 + hi * 4;
    #pragma unroll
    for (int n = 0; n < 4; ++n) {
      const int col = j0 + wc * 64 + n * 16 + lo;
      #pragma unroll
      for (int r = 0; r < 4; ++r) {
        if (OUT_BF16) Cb[(size_t)(row + r) * N + col] = f2bf(acc[m][n][r]);
        else          Cf[(size_t)(row + r) * N + col] = acc[m][n][r];
      }
    }
  }
}

// finish one 32-key half: exp/mask -> pack -> PV (+ones-MFMA row-sum).
// No setprio: let the scheduler interleave this VALU with neighboring MFMA.
#define FINZ(SS, ZZ)                                                          \
  {                                                                           \
    if (fast) {                                                               \
      _Pragma("unroll")                                                       \
      for (int r = 0; r < 16; ++r) SS[r] = EXP2F(SS[r]);                      \
    } else {                                                                  \
      const unsigned pmz = __builtin_amdgcn_readlane(pmword, 2 * t + ZZ);     \
      const int lim = limb - j0 - 32 * ZZ;                                    \
      const unsigned cm = lim < 0 ? 0u : (lim >= 31 ? ~0u : ((2u << lim) - 1u)); \
      const unsigned al = (pmz >> (4 * sb)) | cm;                             \
      _Pragma("unroll")                                                       \
      for (int r = 0; r < 16; ++r) {                                          \
        const int kc = (r & 3) + 8 * (r >> 2);                                \
        const float p = EXP2F(SS[r]);                                         \
        SS[r] = ((al >> kc) & 1) ? p : 0.f;                                   \
      }                                                                       \
    }                                                                         \
    unsigned U0, U1, W0, W1;                                                  \
    U0 = cvtpk_bf16(SS[0], SS[1]);  U1 = cvtpk_bf16(SS[2], SS[3]);            \
    W0 = cvtpk_bf16(SS[4], SS[5]);  W1 = cvtpk_bf16(SS[6], SS[7]);            \
    asm("v_permlane32_swap_b32 %0, %1" : "+v"(U0), "+v"(W0));                 \
    asm("v_permlane32_swap_b32 %0, %1" : "+v"(U1), "+v"(W1));                 \
    union { unsigned u[4]; bf16x8 v; } pu;                                    \
    pu.u[0] = U0; pu.u[1] = U1; pu.u[2] = W0; pu.u[3] = W1;                   \
    const bf16x8 pfA = pu.v;                                                  \
    U0 = cvtpk_bf16(SS[8], SS[9]);   U1 = cvtpk_bf16(SS[10], SS[11]);         \
    W0 = cvtpk_bf16(SS[12], SS[13]); W1 = cvtpk_bf16(SS[14], SS[15]);         \
    asm("v_permlane32_swap_b32 %0, %1" : "+v"(U0), "+v"(W0));                 \
    asm("v_permlane32_swap_b32 %0, %1" : "+v"(U1), "+v"(W1));                 \
    pu.u[0] = U0; pu.u[1] = U1; pu.u[2] = W0; pu.u[3] = W1;                   \
    const bf16x8 pfB = pu.v;                                                  \
    const int swA = ((4 * ZZ + sb) ^ (c & 7)) << 4;                           \
    const int swB = ((4 * ZZ + 2 + sb) ^ (c & 7)) << 4;                       \
    const bf16x8 va0 = *reinterpret_cast<const bf16x8*>(Vb + c * 128 + swA);  \
    const bf16x8 va1 = *reinterpret_cast<const bf16x8*>(Vb + (32 + c) * 128 + swA); \
    const bf16x8 vb0 = *reinterpret_cast<const bf16x8*>(Vb + c * 128 + swB);  \
    const bf16x8 vb1 = *reinterpret_cast<const bf16x8*>(Vb + (32 + c) * 128 + swB); \
    o0 = __builtin_amdgcn_mfma_f32_32x32x16_bf16(va0, pfA, o0, 0, 0, 0);      \
    o1 = __builtin_amdgcn_mfma_f32_32x32x16_bf16(va1, pfA, o1, 0, 0, 0);      \
    ls = __builtin_amdgcn_mfma_f32_32x32x16_bf16(onesv, pfA, ls, 0, 0, 0);    \
    o0 = __builtin_amdgcn_mfma_f32_32x32x16_bf16(vb0, pfB, o0, 0, 0, 0);      \
    o1 = __builtin_amdgcn_mfma_f32_32x32x16_bf16(vb1, pfB, o1, 0, 0, 0);      \
    ls = __builtin_amdgcn_mfma_f32_32x32x16_bf16(onesv, pfB, ls, 0, 0, 0);    \
  }

// ---------------- HSTU flash attention + U gating (32x32 swapped) -----------
// grid (16,16,2); block map: b = dlin>>8 (co-resident pairs span both batches),
// XCD rotate on low 8 bits.  512 threads = 8 waves; 2-way KV split: group
// g = w>>2 handles tiles t=2i+g; wave w owns q-rows i0+(w&3)*32..+31.
// No-max softmax -> partials additive; groups combine through LDS at end.
__global__ __launch_bounds__(512, 4) void hstu_attn(
    const unsigned short* __restrict__ qm,
    const unsigned short* __restrict__ km,
    const unsigned short* __restrict__ vimg,
    const unsigned short* __restrict__ um,
    const unsigned* __restrict__ allowed,
    const int* __restrict__ slens,
    unsigned short* __restrict__ gated)
{
  // smem carve: K[g][buf] 4x8KB at 0..32KB; V[g][buf] 4x8KB at 32..64KB.
  __shared__ char smem[65536];

  const int dlin = blockIdx.x + (blockIdx.y << 4) + (blockIdx.z << 8);
  const int b = dlin >> 8;                           // batch-balanced pairing
  const int r8 = dlin & 255;
  const int lin8 = ((r8 & 7) << 5) | (r8 >> 3);      // XCD rotate (256%8==0)
  const int qt = lin8 & 15, h = lin8 >> 4;
  const int i0 = qt * 128;
  const int tid = threadIdx.x, w = tid >> 6, lane = tid & 63;
  const int g = w >> 2, wq = w & 3;
  const int c = lane & 31, sb = lane >> 5;
  const int seqlen = slens[b];
  const size_t rbm = (size_t)b * L_SEQ * 1024;
  const size_t vbg = (size_t)(b * 16 + h) * 32 * 4096;
  const int qrow = i0 + wq * 32 + c;

  auto stageK = [&](int buf, int t) {
    const int j0 = t * 64;
    char* Kb = smem + (g * 2 + buf) * 8192;
    #pragma unroll
    for (int q = 0; q < 2; ++q) {
      const int p = wq * 2 + q;
      const int krow = 8 * p + (lane >> 3);
      const int d0 = 8 * ((lane & 7) ^ (lane >> 3));
      async16(km + rbm + (size_t)(j0 + krow) * 1024 + h * 64 + d0, Kb + p * 1024);
    }
  };
  auto stageV = [&](int buf, int t) {
    char* Vb = smem + 32768 + (g * 2 + buf) * 8192;
    #pragma unroll
    for (int q = 0; q < 2; ++q) {
      const int p = wq * 2 + q;
      async16(vimg + vbg + (size_t)t * 4096 + p * 512 + lane * 8, Vb + p * 1024);
    }
  };

  const int nt = (seqlen + 63) >> 6;
  const int niter = (nt + 1) >> 1;

  stageK(0, g); stageV(0, g);

  bf16x8 qf[4];
  #pragma unroll
  for (int kd = 0; kd < 4; ++kd)
    qf[kd] = *reinterpret_cast<const bf16x8*>(
        qm + rbm + (size_t)qrow * 1024 + h * 64 + kd * 16 + sb * 8);
  const unsigned pmword = allowed[b * 64 + lane];
  const int limb = (qrow < seqlen - 1 ? qrow : seqlen - 1) - 4 * sb;

  union { unsigned u[4]; bf16x8 v; } one_;
  one_.u[0] = one_.u[1] = one_.u[2] = one_.u[3] = 0x3F803F80u;
  const bf16x8 onesv = one_.v;

  f32x16 o0 = {}, o1 = {}, ls = {};

  asm volatile("s_waitcnt vmcnt(0)" ::: "memory");
  __builtin_amdgcn_s_barrier();
  __builtin_amdgcn_sched_barrier(0);

  for (int i = 0; i < niter; ++i) {
    const int t = 2 * i + g;
    const bool active = t < nt;
    const int buf = i & 1;
    const int j0 = t * 64;
    const bool pre = (t + 2 < nt);

    if (active) {
      if (pre) { stageK(buf ^ 1, t + 2); stageV(buf ^ 1, t + 2); }

      const char* Kb = smem + (g * 2 + buf) * 8192;
      const char* Vb = smem + 32768 + (g * 2 + buf) * 8192;
      const bool fast = (j0 + 64 <= seqlen) && (j0 + 63 <= i0 + wq * 32);

      // interleaved QK: two independent 4-deep MFMA chains (keys 0-31, 32-63)
      f32x16 sE = {}, sO = {};
      #pragma unroll
      for (int kd = 0; kd < 4; ++kd) {
        const int sw = ((2 * kd + sb) ^ (c & 7)) << 4;
        const bf16x8 kfE = *reinterpret_cast<const bf16x8*>(Kb + c * 128 + sw);
        const bf16x8 kfO = *reinterpret_cast<const bf16x8*>(Kb + (32 + c) * 128 + sw);
        sE = __builtin_amdgcn_mfma_f32_32x32x16_bf16(kfE, qf[kd], sE, 0, 0, 0);
        sO = __builtin_amdgcn_mfma_f32_32x32x16_bf16(kfO, qf[kd], sO, 0, 0, 0);
      }

      FINZ(sE, 0)
      FINZ(sO, 1)

      asm volatile("s_waitcnt vmcnt(0)" ::: "memory");
    }
    __builtin_amdgcn_s_barrier();
    __builtin_amdgcn_sched_barrier(0);
  }

  const float lsum = ls[0];

  // ---- combine: odd group dumps partials, even group adds ----
  float* cb = (float*)smem;
  const int col = wq * 64 + lane;
  if (g == 1) {
    #pragma unroll
    for (int r = 0; r < 16; ++r) {
      cb[r * 260 + col]        = o0[r];
      cb[(16 + r) * 260 + col] = o1[r];
    }
    cb[32 * 260 + col] = lsum;
  }
  __syncthreads();
  if (g == 1) return;
  #pragma unroll
  for (int r = 0; r < 16; ++r) {
    o0[r] += cb[r * 260 + col];
    o1[r] += cb[(16 + r) * 260 + col];
  }
  const float rin = 1.0f / (lsum + cb[32 * 260 + col]);

  #pragma unroll
  for (int n = 0; n < 2; ++n) {
    const f32x16 o = n ? o1 : o0;
    #pragma unroll
    for (int rq = 0; rq < 4; ++rq) {
      const int d0 = n * 32 + 8 * rq + 4 * sb;
      const ushort4 uu = *reinterpret_cast<const ushort4*>(
          um + rbm + (size_t)qrow * 1024 + h * 64 + d0);
      ushort4 gg;
      gg.x = f2bf(o[4 * rq + 0] * rin * bf2f(uu.x));
      gg.y = f2bf(o[4 * rq + 1] * rin * bf2f(uu.y));
      gg.z = f2bf(o[4 * rq + 2] * rin * bf2f(uu.z));
      gg.w = f2bf(o[4 * rq + 3] * rin * bf2f(uu.w));
      *reinterpret_cast<ushort4*>(
          gated + (size_t)(b * L_SEQ + qrow) * 1024 + h * 64 + d0) = gg;
    }
  }
}

// ---------------- launch ----------------
extern "C" void kernel_launch(void* const* d_in, const int* in_sizes, int n_in,
                              void* d_out, int out_size, void* d_ws, size_t ws_size,
                              hipStream_t stream) {
  const float* x  = (const float*)d_in[0];
  const int* tt   = (const int*)d_in[1];
  const int* sl   = (const int*)d_in[2];
  const float* Wq = (const float*)d_in[3];
  const float* Wk = (const float*)d_in[4];
  const float* Wv = (const float*)d_in[5];
  const float* Wu = (const float*)d_in[6];
  const float* Wo = (const float*)d_in[7];
  float* out = (float*)d_out;

  // ws layout: allowed[512B] | xb(8MB) | wcat(8MB) | wob(2MB) |
  //            qkvu(32MB: Q|K|Vimg|U 8MB each) | gated(8MB)
  unsigned* allowed     = (unsigned*)d_ws;
  unsigned short* xb    = (unsigned short*)d_ws + 256;
  unsigned short* wcat  = xb    + (size_t)4096 * 1024;
  unsigned short* wob   = wcat  + (size_t)4096 * 1024;
  unsigned short* qkvu  = wob   + (size_t)1024 * 1024;
  unsigned short* gated = qkvu  + (size_t)4096 * 4096;

  // converts + key bitmask in one kernel
  cvt_all<<<9232, 256, 0, stream>>>(x, Wq, Wk, Wv, Wu, Wo, xb, wcat,
                                    tt, sl, allowed);

  // QKVU (4-matrix layout, V as swizzled tile images), 256 blocks, 8-phase
  gemm256_bt<<<256, 512, 0, stream>>>(xb, wcat, qkvu, 1024);

  // attention + gating (512 threads, 8 waves, 2-way KV split, no setprio)
  hstu_attn<<<dim3(16, 16, 2), 512, 0, stream>>>(
      qkvu, qkvu + (size_t)4194304, qkvu + (size_t)2 * 4194304,
      qkvu + (size_t)3 * 4194304, allowed, sl, gated);

  // out = gated @ Wo^T  (M=4096, N=1024, K=1024), 512 blocks of 64x128
  gemm_bt<0, 2><<<dim3(8, 64), 256, 0, stream>>>(gated, wob, out, nullptr,
                                                 4096, 1024, 1024, 64, 7, 3);
}

// Round 19
// 116.321 us; speedup vs baseline: 1.1171x; 1.1171x over previous
//
#include <hip/hip_runtime.h>

// HSTU attention layer: B=2, L=2048, D=1024, H=16, DK=64
// Pipeline: fused fp32->bf16 cvt (+key bitmask; W_q pre-scaled by 0.125*log2e)
// -> QKVU GEMM (256^2 8-phase; V written as swizzled V^T tile images) ->
// flash HSTU attention (swapped 32x32x16, no-max softmax, interleaved QK
// chains, 8 waves, 2-way KV-split, batch-balanced block map, NO setprio in
// the loop) -> gated bf16 -> out GEMM (64x128 m97).

#define L_SEQ 2048

typedef __attribute__((ext_vector_type(8))) short bf16x8;     // MFMA A/B frag
typedef __attribute__((ext_vector_type(8))) unsigned short u16x8;
typedef __attribute__((ext_vector_type(4))) float f32x4;      // 16x16 C/D frag
typedef __attribute__((ext_vector_type(16))) float f32x16;    // 32x32 C/D frag

#if __has_builtin(__builtin_amdgcn_exp2f)
#define EXP2F __builtin_amdgcn_exp2f
#else
#define EXP2F __builtin_exp2f
#endif

__device__ __forceinline__ unsigned short f2bf(float f) {
  union { float f; unsigned u; } c; c.f = f;
  unsigned r = c.u + 0x7FFFu + ((c.u >> 16) & 1u);   // RNE
  return (unsigned short)(r >> 16);
}
__device__ __forceinline__ float bf2f(unsigned short h) {
  union { unsigned u; float f; } c; c.u = ((unsigned)h) << 16;
  return c.f;
}

// async global->LDS, 16B/lane. LDS dest = wave-uniform base + lane*16 (linear).
__device__ __forceinline__ void async16(const void* g, void* l) {
  __builtin_amdgcn_global_load_lds((__attribute__((address_space(1))) void*)g,
                                   (__attribute__((address_space(3))) void*)l,
                                   16, 0, 0);
}

__device__ __forceinline__ unsigned cvtpk_bf16(float lo, float hi) {
  unsigned r; asm("v_cvt_pk_bf16_f32 %0, %1, %2" : "=v"(r) : "v"(lo), "v"(hi));
  return r;
}

// ------- fused convert: x | Wq(scaled) | Wk | Wv | Wu | Wo  + key bitmask ----
// blocks 0..9215: converts.  blocks 9216..9231: "always-allowed" mask words.
__global__ __launch_bounds__(256) void cvt_all(
    const float* __restrict__ x,
    const float* __restrict__ wq, const float* __restrict__ wk,
    const float* __restrict__ wv, const float* __restrict__ wu,
    const float* __restrict__ wo,
    unsigned short* __restrict__ xb, unsigned short* __restrict__ wcat,
    const int* __restrict__ tt, const int* __restrict__ sl,
    unsigned* __restrict__ allowed) {
  if (blockIdx.x >= 9216) {                          // mask blocks
    const int k = blockIdx.x - 9216;                 // 0..15
    const int wv64 = (k << 2) + (threadIdx.x >> 6);  // wave unit 0..63
    const int b = wv64 >> 5, w32 = wv64 & 31;
    const int lane = threadIdx.x & 63;
    const int j = w32 * 64 + lane;
    const unsigned long long m = __ballot((tt[b * L_SEQ + j] < 3) && (j < sl[b]));
    if (lane == 0) {
      allowed[b * 64 + 2 * w32]     = (unsigned)m;
      allowed[b * 64 + 2 * w32 + 1] = (unsigned)(m >> 32);
    }
    return;
  }
  const int seg = blockIdx.x >> 10;
  const float* s;
  unsigned short* d;
  float sc = 1.0f;
  if (seg < 4)      { s = x + (size_t)seg * 1048576;  d = xb + (size_t)seg * 1048576; }
  else {
    const int ws = seg - 4;
    s = ws == 0 ? wq : ws == 1 ? wk : ws == 2 ? wv : ws == 3 ? wu : wo;
    d = wcat + (size_t)ws * 1048576;                  // Wo lands right after Wu (=wob)
    if (ws == 0) sc = 0.18033688011112042f;           // 0.125 * log2(e)
  }
  const int i = ((blockIdx.x & 1023) * 256 + threadIdx.x) * 4;
  const float4 v = *reinterpret_cast<const float4*>(s + i);
  ushort4 o;
  o.x = f2bf(v.x * sc); o.y = f2bf(v.y * sc); o.z = f2bf(v.z * sc); o.w = f2bf(v.w * sc);
  *reinterpret_cast<ushort4*>(d + i) = o;
}

// ---------------- GEMM1: 256x256 tile, BK=64, 8 waves, phase-split ----------
// Out: FOUR 4096x1024 matrices Q|K|V|U at Cb + mi*4M elems.  V-region blocks
// write swizzled 64x64 V^T tile images (attn's exact LDS image).
__global__ __launch_bounds__(512, 2) void gemm256_bt(
    const unsigned short* __restrict__ A,
    const unsigned short* __restrict__ BT,
    unsigned short* __restrict__ Cb, int K)
{
  __shared__ char smem[131072];

  const int tid = threadIdx.x, w = tid >> 6, lane = tid & 63;
  const int lo = lane & 15, hi = lane >> 4;
  const int wm = w >> 2, wn = w & 3;
  const int d = blockIdx.x;
  const int lin = (d & 7) * 32 + (d >> 3);           // XCD swizzle (256%8==0)
  const int i0 = (lin >> 4) * 256, j0 = (lin & 15) * 256;

  const int rr = lane >> 3, ch = lane & 7;
  const int ksw = 8 * (ch ^ rr);                     // pre-swizzled k offset

  auto stage = [&](int buf, int t) {
    const size_t k0 = (size_t)t * 64 + ksw;
    #pragma unroll
    for (int q = 0; q < 2; ++q) {
      const int p = 2 * w + q;                       // window 0..15 (8 rows each)
      const int row = 8 * p + rr;
      #pragma unroll
      for (int h = 0; h < 2; ++h) {
        async16(A  + (size_t)(i0 + h * 128 + row) * K + k0,
                smem + buf * 32768 + h * 16384 + p * 1024);
        async16(BT + (size_t)(j0 + h * 128 + row) * K + k0,
                smem + 65536 + buf * 32768 + h * 16384 + p * 1024);
      }
    }
  };

  f32x4 acc[8][4] = {};
  stage(0, 0);

  const int nt = K >> 6;                             // 16 K-tiles
  for (int u = 0; u < nt; ++u) {
    const int buf = u & 1;
    if (u + 1 < nt) {
      stage(buf ^ 1, u + 1);
      asm volatile("s_waitcnt vmcnt(8)" ::: "memory");  // tile u landed; u+1 in flight
    } else {
      asm volatile("s_waitcnt vmcnt(0)" ::: "memory");
    }
    __builtin_amdgcn_s_barrier();
    __builtin_amdgcn_sched_barrier(0);

    const char* Ah = smem + buf * 32768 + wm * 16384;              // this wave's A half
    const char* Bh = smem + 65536 + buf * 32768 + (wn >> 1) * 16384;
    const int brow0 = (wn & 1) * 64;

    bf16x8 bfr[4][2];                                // B frags cached for the tile
    #pragma unroll
    for (int n = 0; n < 4; ++n)
      #pragma unroll
      for (int ks = 0; ks < 2; ++ks)
        bfr[n][ks] = *reinterpret_cast<const bf16x8*>(
            Bh + (brow0 + n * 16 + lo) * 128 + 16 * ((ks * 4 + hi) ^ (lo & 7)));

    #pragma unroll
    for (int ph = 0; ph < 4; ++ph) {
      bf16x8 afr[2][2];
      #pragma unroll
      for (int mm = 0; mm < 2; ++mm)
        #pragma unroll
        for (int ks = 0; ks < 2; ++ks)
          afr[mm][ks] = *reinterpret_cast<const bf16x8*>(
              Ah + ((ph * 2 + mm) * 16 + lo) * 128 + 16 * ((ks * 4 + hi) ^ (lo & 7)));
      __builtin_amdgcn_s_barrier();
      __builtin_amdgcn_sched_barrier(0);
      __builtin_amdgcn_s_setprio(1);
      #pragma unroll
      for (int ks = 0; ks < 2; ++ks)
        #pragma unroll
        for (int mm = 0; mm < 2; ++mm)
          #pragma unroll
          for (int n = 0; n < 4; ++n)
            acc[ph * 2 + mm][n] = __builtin_amdgcn_mfma_f32_16x16x32_bf16(
                afr[mm][ks], bfr[n][ks], acc[ph * 2 + mm][n], 0, 0, 0);
      __builtin_amdgcn_s_setprio(0);
      __builtin_amdgcn_s_barrier();
      __builtin_amdgcn_sched_barrier(0);
    }
  }

  // ---- epilogue ----
  const int mi = (lin & 15) >> 2;                    // 0:Q 1:K 2:V 3:U
  const int cb0 = j0 & 1023;                         // col base within the matrix
  if (mi != 2) {
    unsigned short* base = Cb + (size_t)mi * 4194304;
    #pragma unroll
    for (int m = 0; m < 8; ++m) {
      const int row = i0 + wm * 128 + m * 16 + hi * 4;
      #pragma unroll
      for (int n = 0; n < 4; ++n) {
        const int col = cb0 + wn * 64 + n * 16 + lo;
        #pragma unroll
        for (int r = 0; r < 4; ++r)
          base[(size_t)(row + r) * 1024 + col] = f2bf(acc[m][n][r]);
      }
    }
  } else {
    // all waves are past the final K-loop barrier -> smem is free
    #pragma unroll
    for (int m = 0; m < 8; ++m) {
      const int tl = (wm << 1) + (m >> 2);           // 64-token tile within block
      #pragma unroll
      for (int n = 0; n < 4; ++n) {
        const int dd = n * 16 + lo;
        char* ib = smem + (tl * 4 + wn) * 8192 + dd * 128;
        const int swd = dd & 7;
        #pragma unroll
        for (int r = 0; r < 4; ++r) {
          const int k = (m * 16 + hi * 4 + r) & 63;
          *(unsigned short*)(ib + 16 * ((k >> 3) ^ swd) + 2 * (k & 7)) =
              f2bf(acc[m][n][r]);
        }
      }
    }
    __builtin_amdgcn_s_barrier();
    unsigned short* V = Cb + (size_t)2 * 4194304;
    const int bI = i0 >> 11;
    const int t0 = (i0 & 2047) >> 6;
    const int h0 = cb0 >> 6;
    #pragma unroll
    for (int img = 0; img < 16; ++img) {
      const int tl = img >> 2, hl = img & 3;
      const size_t ob = ((size_t)(bI * 16 + h0 + hl) * 32 + (t0 + tl)) * 4096;
      *reinterpret_cast<u16x8*>(V + ob + tid * 8) =
          *reinterpret_cast<const u16x8*>(smem + img * 8192 + tid * 16);
    }
  }
}

// ---------------- GEMM (m97): C = A * BT^T, MF*32 x 128 tile ----------------
template<int OUT_BF16, int MF>
__global__ __launch_bounds__(256) void gemm_bt(
    const unsigned short* __restrict__ A,
    const unsigned short* __restrict__ BT,
    float* __restrict__ Cf, unsigned short* __restrict__ Cb,
    int M, int N, int K, int cpx, int nbxm, int nbxs)
{
  __shared__ unsigned short As[2][MF * 32 * 32];
  __shared__ unsigned short Bs[2][128 * 32];

  const int tid = threadIdx.x;
  const int w = tid >> 6, lane = tid & 63;
  const int lo = lane & 15, hi = lane >> 4;
  const int d = blockIdx.x + gridDim.x * blockIdx.y;
  const int lin = (d & 7) * cpx + (d >> 3);
  const int i0 = (lin >> nbxs) * (MF * 32), j0 = (lin & nbxm) * 128;
  const int wr = w >> 1, wc = w & 1;
  const int rsub = lane >> 2, csub = (lane & 3) * 8;

  f32x4 acc[MF][4] = {};

  auto stage = [&](int buf, int k0) {
    #pragma unroll
    for (int q = 0; q < 2; ++q) {
      const int cB = w * 2 + q;
      async16(BT + (size_t)(j0 + cB * 16 + rsub) * K + k0 + csub, &Bs[buf][cB * 512]);
      if (q < MF / 2) {
        const int cA = w * (MF / 2) + q;
        async16(A + (size_t)(i0 + cA * 16 + rsub) * K + k0 + csub, &As[buf][cA * 512]);
      }
    }
  };

  stage(0, 0);
  __syncthreads();

  const int nt = K >> 5;
  for (int t = 0; t < nt; ++t) {
    const int buf = t & 1;
    if (t + 1 < nt) stage(buf ^ 1, (t + 1) << 5);
    bf16x8 a[MF], b[4];
    #pragma unroll
    for (int m = 0; m < MF; ++m)
      a[m] = *reinterpret_cast<const bf16x8*>(
          &As[buf][(wr * (MF * 16) + m * 16 + lo) * 32 + hi * 8]);
    #pragma unroll
    for (int n = 0; n < 4; ++n)
      b[n] = *reinterpret_cast<const bf16x8*>(&Bs[buf][(wc * 64 + n * 16 + lo) * 32 + hi * 8]);
    #pragma unroll
    for (int m = 0; m < MF; ++m)
      #pragma unroll
      for (int n = 0; n < 4; ++n)
        acc[m][n] = __builtin_amdgcn_mfma_f32_16x16x32_bf16(a[m], b[n], acc[m][n], 0, 0, 0);
    __syncthreads();
  }

  #pragma unroll
  for (int m = 0; m < MF; ++m) {
    const int row = i0 + wr * (MF * 16) + m * 16 + hi * 4;
    #pragma unroll
    for (int n = 0; n < 4; ++n) {
      const int col = j0 + wc * 64 + n * 16 + lo;
      #pragma unroll
      for (int r = 0; r < 4; ++r) {
        if (OUT_BF16) Cb[(size_t)(row + r) * N + col] = f2bf(acc[m][n][r]);
        else          Cf[(size_t)(row + r) * N + col] = acc[m][n][r];
      }
    }
  }
}

// finish one 32-key half: exp/mask (+rs) -> pack -> PV.  No setprio.
#define FINZ(SS, ZZ)                                                          \
  {                                                                           \
    if (fast) {                                                               \
      _Pragma("unroll")                                                       \
      for (int r = 0; r < 16; ++r) { SS[r] = EXP2F(SS[r]); rs += SS[r]; }     \
    } else {                                                                  \
      const unsigned pmz = __builtin_amdgcn_readlane(pmword, 2 * t + ZZ);     \
      const int lim = limb - j0 - 32 * ZZ;                                    \
      const unsigned cm = lim < 0 ? 0u : (lim >= 31 ? ~0u : ((2u << lim) - 1u)); \
      const unsigned al = (pmz >> (4 * sb)) | cm;                             \
      _Pragma("unroll")                                                       \
      for (int r = 0; r < 16; ++r) {                                          \
        const int kc = (r & 3) + 8 * (r >> 2);                                \
        const float p = EXP2F(SS[r]);                                         \
        SS[r] = ((al >> kc) & 1) ? p : 0.f;                                   \
        rs += SS[r];                                                          \
      }                                                                       \
    }                                                                         \
    unsigned U0, U1, W0, W1;                                                  \
    U0 = cvtpk_bf16(SS[0], SS[1]);  U1 = cvtpk_bf16(SS[2], SS[3]);            \
    W0 = cvtpk_bf16(SS[4], SS[5]);  W1 = cvtpk_bf16(SS[6], SS[7]);            \
    asm("v_permlane32_swap_b32 %0, %1" : "+v"(U0), "+v"(W0));                 \
    asm("v_permlane32_swap_b32 %0, %1" : "+v"(U1), "+v"(W1));                 \
    union { unsigned u[4]; bf16x8 v; } pu;                                    \
    pu.u[0] = U0; pu.u[1] = U1; pu.u[2] = W0; pu.u[3] = W1;                   \
    const bf16x8 pfA = pu.v;                                                  \
    U0 = cvtpk_bf16(SS[8], SS[9]);   U1 = cvtpk_bf16(SS[10], SS[11]);         \
    W0 = cvtpk_bf16(SS[12], SS[13]); W1 = cvtpk_bf16(SS[14], SS[15]);         \
    asm("v_permlane32_swap_b32 %0, %1" : "+v"(U0), "+v"(W0));                 \
    asm("v_permlane32_swap_b32 %0, %1" : "+v"(U1), "+v"(W1));                 \
    pu.u[0] = U0; pu.u[1] = U1; pu.u[2] = W0; pu.u[3] = W1;                   \
    const bf16x8 pfB = pu.v;                                                  \
    const int swA = ((4 * ZZ + sb) ^ (c & 7)) << 4;                           \
    const int swB = ((4 * ZZ + 2 + sb) ^ (c & 7)) << 4;                       \
    const bf16x8 va0 = *reinterpret_cast<const bf16x8*>(Vb + c * 128 + swA);  \
    const bf16x8 va1 = *reinterpret_cast<const bf16x8*>(Vb + (32 + c) * 128 + swA); \
    const bf16x8 vb0 = *reinterpret_cast<const bf16x8*>(Vb + c * 128 + swB);  \
    const bf16x8 vb1 = *reinterpret_cast<const bf16x8*>(Vb + (32 + c) * 128 + swB); \
    o0 = __builtin_amdgcn_mfma_f32_32x32x16_bf16(va0, pfA, o0, 0, 0, 0);      \
    o1 = __builtin_amdgcn_mfma_f32_32x32x16_bf16(va1, pfA, o1, 0, 0, 0);      \
    o0 = __builtin_amdgcn_mfma_f32_32x32x16_bf16(vb0, pfB, o0, 0, 0, 0);      \
    o1 = __builtin_amdgcn_mfma_f32_32x32x16_bf16(vb1, pfB, o1, 0, 0, 0);      \
  }

// ---------------- HSTU flash attention + U gating (32x32 swapped) -----------
// grid (16,16,2); block map: b = dlin>>8 (co-resident pairs span both batches),
// XCD rotate on low 8 bits.  512 threads = 8 waves; 2-way KV split: group
// g = w>>2 handles tiles t=2i+g; wave w owns q-rows i0+(w&3)*32..+31.
// No-max softmax -> partials additive; groups combine through LDS at end.
__global__ __launch_bounds__(512, 4) void hstu_attn(
    const unsigned short* __restrict__ qm,
    const unsigned short* __restrict__ km,
    const unsigned short* __restrict__ vimg,
    const unsigned short* __restrict__ um,
    const unsigned* __restrict__ allowed,
    const int* __restrict__ slens,
    unsigned short* __restrict__ gated)
{
  // smem carve: K[g][buf] 4x8KB at 0..32KB; V[g][buf] 4x8KB at 32..64KB.
  __shared__ char smem[65536];

  const int dlin = blockIdx.x + (blockIdx.y << 4) + (blockIdx.z << 8);
  const int b = dlin >> 8;                           // batch-balanced pairing
  const int r8 = dlin & 255;
  const int lin8 = ((r8 & 7) << 5) | (r8 >> 3);      // XCD rotate (256%8==0)
  const int qt = lin8 & 15, h = lin8 >> 4;
  const int i0 = qt * 128;
  const int tid = threadIdx.x, w = tid >> 6, lane = tid & 63;
  const int g = w >> 2, wq = w & 3;
  const int c = lane & 31, sb = lane >> 5;
  const int seqlen = slens[b];
  const size_t rbm = (size_t)b * L_SEQ * 1024;
  const size_t vbg = (size_t)(b * 16 + h) * 32 * 4096;
  const int qrow = i0 + wq * 32 + c;

  auto stageK = [&](int buf, int t) {
    const int j0 = t * 64;
    char* Kb = smem + (g * 2 + buf) * 8192;
    #pragma unroll
    for (int q = 0; q < 2; ++q) {
      const int p = wq * 2 + q;
      const int krow = 8 * p + (lane >> 3);
      const int d0 = 8 * ((lane & 7) ^ (lane >> 3));
      async16(km + rbm + (size_t)(j0 + krow) * 1024 + h * 64 + d0, Kb + p * 1024);
    }
  };
  auto stageV = [&](int buf, int t) {
    char* Vb = smem + 32768 + (g * 2 + buf) * 8192;
    #pragma unroll
    for (int q = 0; q < 2; ++q) {
      const int p = wq * 2 + q;
      async16(vimg + vbg + (size_t)t * 4096 + p * 512 + lane * 8, Vb + p * 1024);
    }
  };

  const int nt = (seqlen + 63) >> 6;
  const int niter = (nt + 1) >> 1;

  stageK(0, g); stageV(0, g);

  bf16x8 qf[4];
  #pragma unroll
  for (int kd = 0; kd < 4; ++kd)
    qf[kd] = *reinterpret_cast<const bf16x8*>(
        qm + rbm + (size_t)qrow * 1024 + h * 64 + kd * 16 + sb * 8);
  const unsigned pmword = allowed[b * 64 + lane];
  const int limb = (qrow < seqlen - 1 ? qrow : seqlen - 1) - 4 * sb;

  f32x16 o0 = {}, o1 = {};
  float rs = 0.f;

  asm volatile("s_waitcnt vmcnt(0)" ::: "memory");
  __builtin_amdgcn_s_barrier();
  __builtin_amdgcn_sched_barrier(0);

  for (int i = 0; i < niter; ++i) {
    const int t = 2 * i + g;
    const bool active = t < nt;
    const int buf = i & 1;
    const int j0 = t * 64;
    const bool pre = (t + 2 < nt);

    if (active) {
      if (pre) { stageK(buf ^ 1, t + 2); stageV(buf ^ 1, t + 2); }

      const char* Kb = smem + (g * 2 + buf) * 8192;
      const char* Vb = smem + 32768 + (g * 2 + buf) * 8192;
      const bool fast = (j0 + 64 <= seqlen) && (j0 + 63 <= i0 + wq * 32);

      // interleaved QK: two independent 4-deep MFMA chains (keys 0-31, 32-63)
      f32x16 sE = {}, sO = {};
      #pragma unroll
      for (int kd = 0; kd < 4; ++kd) {
        const int sw = ((2 * kd + sb) ^ (c & 7)) << 4;
        const bf16x8 kfE = *reinterpret_cast<const bf16x8*>(Kb + c * 128 + sw);
        const bf16x8 kfO = *reinterpret_cast<const bf16x8*>(Kb + (32 + c) * 128 + sw);
        sE = __builtin_amdgcn_mfma_f32_32x32x16_bf16(kfE, qf[kd], sE, 0, 0, 0);
        sO = __builtin_amdgcn_mfma_f32_32x32x16_bf16(kfO, qf[kd], sO, 0, 0, 0);
      }

      FINZ(sE, 0)
      FINZ(sO, 1)

      asm volatile("s_waitcnt vmcnt(0)" ::: "memory");
    }
    __builtin_amdgcn_s_barrier();
    __builtin_amdgcn_sched_barrier(0);
  }

  const float lsum = rs + __shfl_xor(rs, 32, 64);

  // ---- combine: odd group dumps partials, even group adds ----
  float* cb = (float*)smem;
  const int col = wq * 64 + lane;
  if (g == 1) {
    #pragma unroll
    for (int r = 0; r < 16; ++r) {
      cb[r * 260 + col]        = o0[r];
      cb[(16 + r) * 260 + col] = o1[r];
    }
    cb[32 * 260 + col] = lsum;
  }
  __syncthreads();
  if (g == 1) return;
  #pragma unroll
  for (int r = 0; r < 16; ++r) {
    o0[r] += cb[r * 260 + col];
    o1[r] += cb[(16 + r) * 260 + col];
  }
  const float rin = 1.0f / (lsum + cb[32 * 260 + col]);

  #pragma unroll
  for (int n = 0; n < 2; ++n) {
    const f32x16 o = n ? o1 : o0;
    #pragma unroll
    for (int rq = 0; rq < 4; ++rq) {
      const int d0 = n * 32 + 8 * rq + 4 * sb;
      const ushort4 uu = *reinterpret_cast<const ushort4*>(
          um + rbm + (size_t)qrow * 1024 + h * 64 + d0);
      ushort4 gg;
      gg.x = f2bf(o[4 * rq + 0] * rin * bf2f(uu.x));
      gg.y = f2bf(o[4 * rq + 1] * rin * bf2f(uu.y));
      gg.z = f2bf(o[4 * rq + 2] * rin * bf2f(uu.z));
      gg.w = f2bf(o[4 * rq + 3] * rin * bf2f(uu.w));
      *reinterpret_cast<ushort4*>(
          gated + (size_t)(b * L_SEQ + qrow) * 1024 + h * 64 + d0) = gg;
    }
  }
}

// ---------------- launch ----------------
extern "C" void kernel_launch(void* const* d_in, const int* in_sizes, int n_in,
                              void* d_out, int out_size, void* d_ws, size_t ws_size,
                              hipStream_t stream) {
  const float* x  = (const float*)d_in[0];
  const int* tt   = (const int*)d_in[1];
  const int* sl   = (const int*)d_in[2];
  const float* Wq = (const float*)d_in[3];
  const float* Wk = (const float*)d_in[4];
  const float* Wv = (const float*)d_in[5];
  const float* Wu = (const float*)d_in[6];
  const float* Wo = (const float*)d_in[7];
  float* out = (float*)d_out;

  // ws layout: allowed[512B] | xb(8MB) | wcat(8MB) | wob(2MB) |
  //            qkvu(32MB: Q|K|Vimg|U 8MB each) | gated(8MB)
  unsigned* allowed     = (unsigned*)d_ws;
  unsigned short* xb    = (unsigned short*)d_ws + 256;
  unsigned short* wcat  = xb    + (size_t)4096 * 1024;
  unsigned short* wob   = wcat  + (size_t)4096 * 1024;
  unsigned short* qkvu  = wob   + (size_t)1024 * 1024;
  unsigned short* gated = qkvu  + (size_t)4096 * 4096;

  // converts + key bitmask in one kernel
  cvt_all<<<9232, 256, 0, stream>>>(x, Wq, Wk, Wv, Wu, Wo, xb, wcat,
                                    tt, sl, allowed);

  // QKVU (4-matrix layout, V as swizzled tile images), 256 blocks, 8-phase
  gemm256_bt<<<256, 512, 0, stream>>>(xb, wcat, qkvu, 1024);

  // attention + gating (512 threads, 8 waves, 2-way KV split, no setprio)
  hstu_attn<<<dim3(16, 16, 2), 512, 0, stream>>>(
      qkvu, qkvu + (size_t)4194304, qkvu + (size_t)2 * 4194304,
      qkvu + (size_t)3 * 4194304, allowed, sl, gated);

  // out = gated @ Wo^T  (M=4096, N=1024, K=1024), 512 blocks of 64x128
  gemm_bt<0, 2><<<dim3(8, 64), 256, 0, stream>>>(gated, wob, out, nullptr,
                                                 4096, 1024, 1024, 64, 7, 3);
}